// Round 3
// baseline (16635.286 us; speedup 1.0000x reference)
//
#include <hip/hip_runtime.h>

// VanillaRNNLayer: B=32, T=2048, I=512, H=512 — ALL FP32 (reference output is fp32!)
//   phase 1: xp = x @ Wx^T + bx + bh   -> written fp32 into d_out[0 .. B*T*H)
//   phase 2: h_t = tanh(xp_t + Wh h_{t-1}) -> overwrites d_out in place, row by row
// d_out layout: outputs [B,T,H] fp32, then h_last [B,H] fp32.
// R1/R2 failure root cause: wrote bf16 into an fp32 output buffer
// (absmax 2.0078125 == ref 1.0 vs two bf16s glued = 0xBF810000 = -1.0078125).

constexpr int Bb = 32, Tt = 2048, Ii = 512, Hh = 512;

// ---------------- Phase 1: xp GEMM (fp32) ----------------
// xp[m][n] = sum_k x[m][k]*Wx[n][k] + bx[n]+bh[n];  M=65536, N=512, K=512 (NT)
__global__ __launch_bounds__(256)
void xproj_gemm(const float* __restrict__ x, const float* __restrict__ Wx,
                const float* __restrict__ bx, const float* __restrict__ bh,
                float* __restrict__ xp)
{
    constexpr int BM = 64, BN = 64, BK = 32, PAD = 4;
    __shared__ float As[BM][BK + PAD];
    __shared__ float Bs[BN][BK + PAD];

    const int tid = threadIdx.x;
    const int tx = tid & 15, ty = tid >> 4;
    const int m0 = blockIdx.x * BM, n0 = blockIdx.y * BN;
    const int lrow = tid >> 2;            // 0..63
    const int lcol = (tid & 3) * 8;       // 0,8,16,24

    float acc[4][4] = {};

    for (int k0 = 0; k0 < Ii; k0 += BK) {
        float4 a0 = *reinterpret_cast<const float4*>(&x[(size_t)(m0 + lrow) * Ii + k0 + lcol]);
        float4 a1 = *reinterpret_cast<const float4*>(&x[(size_t)(m0 + lrow) * Ii + k0 + lcol + 4]);
        float4 b0 = *reinterpret_cast<const float4*>(&Wx[(size_t)(n0 + lrow) * Ii + k0 + lcol]);
        float4 b1 = *reinterpret_cast<const float4*>(&Wx[(size_t)(n0 + lrow) * Ii + k0 + lcol + 4]);
        __syncthreads();   // previous iter's LDS reads done before overwrite
        *reinterpret_cast<float4*>(&As[lrow][lcol])     = a0;
        *reinterpret_cast<float4*>(&As[lrow][lcol + 4]) = a1;
        *reinterpret_cast<float4*>(&Bs[lrow][lcol])     = b0;
        *reinterpret_cast<float4*>(&Bs[lrow][lcol + 4]) = b1;
        __syncthreads();
        #pragma unroll
        for (int k = 0; k < BK; ++k) {
            float av[4], bv[4];
            #pragma unroll
            for (int i = 0; i < 4; ++i) av[i] = As[ty * 4 + i][k];
            #pragma unroll
            for (int i = 0; i < 4; ++i) bv[i] = Bs[tx * 4 + i][k];
            #pragma unroll
            for (int i = 0; i < 4; ++i)
                #pragma unroll
                for (int jj = 0; jj < 4; ++jj)
                    acc[i][jj] += av[i] * bv[jj];
        }
    }

    float bias[4];
    #pragma unroll
    for (int jj = 0; jj < 4; ++jj) {
        int n = n0 + tx * 4 + jj;
        bias[jj] = bx[n] + bh[n];
    }
    #pragma unroll
    for (int i = 0; i < 4; ++i) {
        float4 o = make_float4(acc[i][0] + bias[0], acc[i][1] + bias[1],
                               acc[i][2] + bias[2], acc[i][3] + bias[3]);
        *reinterpret_cast<float4*>(&xp[(size_t)(m0 + ty * 4 + i) * Hh + n0 + tx * 4]) = o;
    }
}

// ---------------- Repack Wh: W4[(c4*512+j)*4+i] = Wh[j][4*c4+i] ----------------
// Scan's weight load becomes one coalesced dwordx4 per lane.
__global__ __launch_bounds__(256)
void repack4(const float* __restrict__ W, float* __restrict__ W4)
{
    int o = blockIdx.x * 256 + threadIdx.x;      // 0..262143
    int i  = o & 3;
    int j  = (o >> 2) & 511;
    int c4 = o >> 11;
    W4[o] = W[(size_t)j * 512 + c4 * 4 + i];
}

// ---------------- Phase 2: sequential scan, one block per batch chain ----------------
// REPACKED=1: W points to W4, thread j's c4-th float4 at W[(c4*512 + j)*4].
// REPACKED=0: W points to raw Wh, float4 at W[j*512 + c4*4] (uncoalesced fallback).
template <bool REPACKED>
__global__ __launch_bounds__(512)
void rnn_scan(const float* __restrict__ W, const float* __restrict__ h0,
              float* __restrict__ out)
{
    const int b = blockIdx.x;        // 0..31
    const int j = threadIdx.x;       // 0..511 : hidden unit owned by this thread
    __shared__ float hs[2][Hh];      // double-buffered -> 1 barrier/step
    hs[0][j] = h0[(size_t)b * Hh + j];
    __syncthreads();

    float* ob = out + (size_t)b * Tt * Hh;   // holds xp now; overwritten with h
    const float* wbase = REPACKED ? (W + (size_t)j * 4) : (W + (size_t)j * Hh);
    constexpr size_t WSTRIDE = REPACKED ? (size_t)Hh * 4 : 4;   // floats per c4 step

    float xp_cur = ob[j];            // xp for t=0
    int cur = 0;
    for (int t = 0; t < Tt; ++t) {
        // prefetch next row's xp BEFORE this row is overwritten (in-place safety:
        // row t+1 is only written at iteration t+1, after this read)
        float xp_next = (t + 1 < Tt) ? ob[(size_t)(t + 1) * Hh + j] : 0.0f;

        float4 a = make_float4(xp_cur, 0.0f, 0.0f, 0.0f);   // 4 independent FMA chains
        const float* h = hs[cur];
        const float* wp = wbase;
        #pragma unroll 8
        for (int c4 = 0; c4 < Hh / 4; ++c4) {
            float4 w  = *reinterpret_cast<const float4*>(wp);
            float4 hv = *reinterpret_cast<const float4*>(&h[c4 * 4]);  // LDS broadcast
            a.x += w.x * hv.x;
            a.y += w.y * hv.y;
            a.z += w.z * hv.z;
            a.w += w.w * hv.w;
            wp += WSTRIDE;
        }
        float hn = tanhf((a.x + a.y) + (a.z + a.w));

        hs[cur ^ 1][j] = hn;               // write other buffer: no read/write race
        ob[(size_t)t * Hh + j] = hn;       // fp32 output (overwrites consumed xp)
        xp_cur = xp_next;
        cur ^= 1;
        __syncthreads();                   // new h visible before next step's reads
    }
    out[(size_t)Bb * Tt * Hh + (size_t)b * Hh + j] = hs[cur][j];   // h_last
}

extern "C" void kernel_launch(void* const* d_in, const int* in_sizes, int n_in,
                              void* d_out, int out_size, void* d_ws, size_t ws_size,
                              hipStream_t stream)
{
    const float* x  = (const float*)d_in[0];
    const float* h0 = (const float*)d_in[1];
    const float* Wx = (const float*)d_in[2];
    const float* bx = (const float*)d_in[3];
    const float* Wh = (const float*)d_in[4];
    const float* bh = (const float*)d_in[5];
    float* out = (float*)d_out;

    // Phase 1: xp -> d_out (in-place consumed by scan)
    dim3 g1(Bb * Tt / 64, Hh / 64);
    xproj_gemm<<<g1, 256, 0, stream>>>(x, Wx, bx, bh, out);

    const size_t w4_bytes = (size_t)Hh * Hh * sizeof(float);   // 1 MB
    if (ws_size >= w4_bytes) {
        float* W4 = (float*)d_ws;
        repack4<<<(Hh * Hh) / 256, 256, 0, stream>>>(Wh, W4);
        rnn_scan<true><<<Bb, Hh, 0, stream>>>(W4, h0, out);
    } else {
        rnn_scan<false><<<Bb, Hh, 0, stream>>>(Wh, h0, out);
    }
}

// Round 4
// 5196.054 us; speedup vs baseline: 3.2015x; 3.2015x over previous
//
#include <hip/hip_runtime.h>

// VanillaRNNLayer: B=32, T=2048, I=512, H=512 — ALL FP32.
//   phase 1: xp = x @ Wx^T + bx + bh   -> fp32 into d_out (consumed in place)
//   phase 2: h_t = tanh(xp_t + Wh h_{t-1})
// R3 analysis: 1 CU/chain streams 1 MB of Wh per step from L2 at the per-CU
// ~150 GB/s ceiling -> 7.4 us/step. Fix: 4 blocks per chain, Wh slice
// register-resident (128 VGPR/thread), h exchanged via agent-scope atomics.

constexpr int Bb = 32, Tt = 2048, Ii = 512, Hh = 512;

// ---------------- Phase 1: xp GEMM (fp32) ----------------
__global__ __launch_bounds__(256)
void xproj_gemm(const float* __restrict__ x, const float* __restrict__ Wx,
                const float* __restrict__ bx, const float* __restrict__ bh,
                float* __restrict__ xp)
{
    constexpr int BM = 64, BN = 64, BK = 32, PAD = 4;
    __shared__ float As[BM][BK + PAD];
    __shared__ float Bs[BN][BK + PAD];

    const int tid = threadIdx.x;
    const int tx = tid & 15, ty = tid >> 4;
    const int m0 = blockIdx.x * BM, n0 = blockIdx.y * BN;
    const int lrow = tid >> 2;
    const int lcol = (tid & 3) * 8;

    float acc[4][4] = {};

    for (int k0 = 0; k0 < Ii; k0 += BK) {
        float4 a0 = *reinterpret_cast<const float4*>(&x[(size_t)(m0 + lrow) * Ii + k0 + lcol]);
        float4 a1 = *reinterpret_cast<const float4*>(&x[(size_t)(m0 + lrow) * Ii + k0 + lcol + 4]);
        float4 b0 = *reinterpret_cast<const float4*>(&Wx[(size_t)(n0 + lrow) * Ii + k0 + lcol]);
        float4 b1 = *reinterpret_cast<const float4*>(&Wx[(size_t)(n0 + lrow) * Ii + k0 + lcol + 4]);
        __syncthreads();
        *reinterpret_cast<float4*>(&As[lrow][lcol])     = a0;
        *reinterpret_cast<float4*>(&As[lrow][lcol + 4]) = a1;
        *reinterpret_cast<float4*>(&Bs[lrow][lcol])     = b0;
        *reinterpret_cast<float4*>(&Bs[lrow][lcol + 4]) = b1;
        __syncthreads();
        #pragma unroll
        for (int k = 0; k < BK; ++k) {
            float av[4], bv[4];
            #pragma unroll
            for (int i = 0; i < 4; ++i) av[i] = As[ty * 4 + i][k];
            #pragma unroll
            for (int i = 0; i < 4; ++i) bv[i] = Bs[tx * 4 + i][k];
            #pragma unroll
            for (int i = 0; i < 4; ++i)
                #pragma unroll
                for (int jj = 0; jj < 4; ++jj)
                    acc[i][jj] += av[i] * bv[jj];
        }
    }

    float bias[4];
    #pragma unroll
    for (int jj = 0; jj < 4; ++jj) {
        int n = n0 + tx * 4 + jj;
        bias[jj] = bx[n] + bh[n];
    }
    #pragma unroll
    for (int i = 0; i < 4; ++i) {
        float4 o = make_float4(acc[i][0] + bias[0], acc[i][1] + bias[1],
                               acc[i][2] + bias[2], acc[i][3] + bias[3]);
        *reinterpret_cast<float4*>(&xp[(size_t)(m0 + ty * 4 + i) * Hh + n0 + tx * 4]) = o;
    }
}

// ---------------- zero the sync flags (fresh every launch: tags are monotonic) --------
__global__ void zero_flags(unsigned int* __restrict__ flags)
{
    flags[threadIdx.x] = 0u;      // 256 u32 = 32 chains x 4 parts x 2 slots
}

// ---------------- Phase 2: multi-block scan, 4 blocks per chain ----------------
// block bid: chain c = bid&31, part P = bid>>5 (P*32+c keeps parts on one XCD
// under round-robin placement; correctness doesn't depend on it).
// Thread (w=tid>>6, lane): owns rows P*128 + w*16 + (lane>>5)*8 + s (s=0..7),
// cols (lane&31)*16 .. +16. Weights: 32 float4 = 128 VGPRs, loaded once.
__global__ __launch_bounds__(512, 2)
void rnn_scan_mb(const float* __restrict__ Wh, const float* __restrict__ h0,
                 float* __restrict__ out, unsigned int* __restrict__ flags,
                 float* __restrict__ xbuf)
{
    const int bid = blockIdx.x;
    const int c = bid & 31;
    const int P = bid >> 5;
    const int tid = threadIdx.x;
    const int w = tid >> 6, lane = tid & 63;
    const int lp = lane & 31, hf = lane >> 5;
    const int col0 = lp * 16;
    const int lrow0 = w * 16 + hf * 8;         // local row base 0..120
    const int grow0 = P * 128 + lrow0;

    __shared__ float hs[512];
    __shared__ float pacc[32][132];            // [col-part][local row], pad->2-way free reads

    // weights -> registers (one-time; 1 MB unique chip-wide, L2/L3 amortized 32x)
    float4 wreg[8][4];
    #pragma unroll
    for (int s = 0; s < 8; ++s)
        #pragma unroll
        for (int q = 0; q < 4; ++q)
            wreg[s][q] = *reinterpret_cast<const float4*>(
                &Wh[(size_t)(grow0 + s) * Hh + col0 + q * 4]);

    hs[tid] = h0[(size_t)c * Hh + tid];

    float* ob = out + (size_t)c * Tt * Hh;          // chain's [T,H] slab (xp -> h in place)
    unsigned int* flg = flags + (size_t)c * 8;      // [part*2 + slot]
    float* xb = xbuf + (size_t)c * 1024;            // [slot*512 + part*128 + r]

    float xp_cur = 0.f;
    if (tid < 128) xp_cur = ob[P * 128 + tid];      // xp row t=0

    __syncthreads();                                 // hs ready

    for (int t = 0; t < Tt; ++t) {
        // ---- partial dot: 8 rows x 16 cols off LDS-broadcast h
        float hvreg[16];
        #pragma unroll
        for (int q = 0; q < 4; ++q) {
            float4 h4 = *reinterpret_cast<const float4*>(&hs[col0 + q * 4]);
            hvreg[q * 4 + 0] = h4.x; hvreg[q * 4 + 1] = h4.y;
            hvreg[q * 4 + 2] = h4.z; hvreg[q * 4 + 3] = h4.w;
        }
        float acc[8];
        #pragma unroll
        for (int s = 0; s < 8; ++s) {
            float a = 0.f;
            #pragma unroll
            for (int q = 0; q < 4; ++q) {
                const float* wq = reinterpret_cast<const float*>(&wreg[s][q]);
                a += wq[0] * hvreg[q * 4 + 0];
                a += wq[1] * hvreg[q * 4 + 1];
                a += wq[2] * hvreg[q * 4 + 2];
                a += wq[3] * hvreg[q * 4 + 3];
            }
            acc[s] = a;
        }
        #pragma unroll
        for (int s = 0; s < 8; s += 4)
            *reinterpret_cast<float4*>(&pacc[lp][lrow0 + s]) =
                make_float4(acc[s], acc[s + 1], acc[s + 2], acc[s + 3]);
        __syncthreads();                             // pacc ready; hs reads done

        const int d = t & 1;
        if (tid < 128) {
            float ssum = xp_cur;
            #pragma unroll
            for (int p = 0; p < 32; ++p) ssum += pacc[p][tid];
            float hval = tanhf(ssum);
            ob[(size_t)t * Hh + P * 128 + tid] = hval;   // final output row-slice
            hs[P * 128 + tid] = hval;                    // own part for next step
            if (t + 1 < Tt) {
                __hip_atomic_store(&xb[d * 512 + P * 128 + tid], hval,
                                   __ATOMIC_RELAXED, __HIP_MEMORY_SCOPE_AGENT);
                xp_cur = ob[(size_t)(t + 1) * Hh + P * 128 + tid];  // prefetch next xp
            }
        }
        __syncthreads();     // drains vmcnt: sc1 stores at coherence point before flag
        if (t + 1 >= Tt) break;
        if (tid == 0)
            __hip_atomic_store(&flg[P * 2 + d], (unsigned)(t + 1),
                               __ATOMIC_RELAXED, __HIP_MEMORY_SCOPE_AGENT);
        if (tid < 4 && tid != P) {
            while (__hip_atomic_load(&flg[tid * 2 + d], __ATOMIC_RELAXED,
                                     __HIP_MEMORY_SCOPE_AGENT) < (unsigned)(t + 1)) {
                __builtin_amdgcn_s_sleep(1);
            }
        }
        __syncthreads();                             // flags observed
        {
            const int p = tid >> 7, r = tid & 127;
            if (p != P)
                hs[tid] = __hip_atomic_load(&xb[d * 512 + p * 128 + r],
                                            __ATOMIC_RELAXED, __HIP_MEMORY_SCOPE_AGENT);
        }
        __syncthreads();                             // hs ready for next step
    }

    if (tid < 128)
        out[(size_t)Bb * Tt * Hh + (size_t)c * Hh + P * 128 + tid] = hs[P * 128 + tid];
}

// ---------------- Fallback single-block scan (tiny ws) ----------------
__global__ __launch_bounds__(512)
void rnn_scan_sb(const float* __restrict__ W, const float* __restrict__ h0,
                 float* __restrict__ out)
{
    const int b = blockIdx.x;
    const int j = threadIdx.x;
    __shared__ float hs[2][Hh];
    hs[0][j] = h0[(size_t)b * Hh + j];
    __syncthreads();

    float* ob = out + (size_t)b * Tt * Hh;
    const float* wbase = W + (size_t)j * Hh;

    float xp_cur = ob[j];
    int cur = 0;
    for (int t = 0; t < Tt; ++t) {
        float xp_next = (t + 1 < Tt) ? ob[(size_t)(t + 1) * Hh + j] : 0.0f;
        float4 a = make_float4(xp_cur, 0.0f, 0.0f, 0.0f);
        const float* h = hs[cur];
        #pragma unroll 8
        for (int c4 = 0; c4 < Hh / 4; ++c4) {
            float4 w  = *reinterpret_cast<const float4*>(&wbase[c4 * 4]);
            float4 hv = *reinterpret_cast<const float4*>(&h[c4 * 4]);
            a.x += w.x * hv.x; a.y += w.y * hv.y;
            a.z += w.z * hv.z; a.w += w.w * hv.w;
        }
        float hn = tanhf((a.x + a.y) + (a.z + a.w));
        hs[cur ^ 1][j] = hn;
        ob[(size_t)t * Hh + j] = hn;
        xp_cur = xp_next;
        cur ^= 1;
        __syncthreads();
    }
    out[(size_t)Bb * Tt * Hh + (size_t)b * Hh + j] = hs[cur][j];
}

extern "C" void kernel_launch(void* const* d_in, const int* in_sizes, int n_in,
                              void* d_out, int out_size, void* d_ws, size_t ws_size,
                              hipStream_t stream)
{
    const float* x  = (const float*)d_in[0];
    const float* h0 = (const float*)d_in[1];
    const float* Wx = (const float*)d_in[2];
    const float* bx = (const float*)d_in[3];
    const float* Wh = (const float*)d_in[4];
    const float* bh = (const float*)d_in[5];
    float* out = (float*)d_out;

    dim3 g1(Bb * Tt / 64, Hh / 64);
    xproj_gemm<<<g1, 256, 0, stream>>>(x, Wx, bx, bh, out);

    const size_t need = 1024 + (size_t)32 * 1024 * sizeof(float);   // flags + xbuf
    if (ws_size >= need) {
        unsigned int* flags = (unsigned int*)d_ws;
        float* xbuf = (float*)((char*)d_ws + 1024);
        zero_flags<<<1, 256, 0, stream>>>(flags);
        void* args[] = {(void*)&Wh, (void*)&h0, (void*)&out, (void*)&flags, (void*)&xbuf};
        hipLaunchCooperativeKernel((void*)rnn_scan_mb, dim3(128), dim3(512),
                                   args, 0, stream);
    } else {
        rnn_scan_sb<<<Bb, Hh, 0, stream>>>(Wh, h0, out);
    }
}